// Round 7
// baseline (355.097 us; speedup 1.0000x reference)
//
#include <hip/hip_runtime.h>
#include <math.h>
#include <stdint.h>

#define H 512
#define W 512
#define NPIX (H * W)          // 262144
#define NB 2
#define NF 180
#define KS 17
#define WSCALE 1024.0f        // exact power of two; cancels in both outputs

// LDS pool (u32 offsets): raw rows 18*80=1440; B double buffer 2*3*3072=18432
#define RAW_OFF 0
#define BB_OFF  1440
#define BCH_U32 3072          // one K-chunk of B (hi+lo, N=192), 12 KB
#define BUF_U32 (3 * BCH_U32) // 3-chunk phase buffer, 36 KB
#define POOL_U32 (1440 + 2 * BUF_U32)   // 19872 u32 = 79.5 KB -> 2 blocks/CU

typedef _Float16 half8 __attribute__((ext_vector_type(8)));
typedef float floatx16 __attribute__((ext_vector_type(16)));
typedef uint32_t u32x4 __attribute__((ext_vector_type(4)));

union FragU { u32x4 u; half8 h; };

__device__ inline void gl_lds16(const uint32_t* g, uint32_t* l) {
  __builtin_amdgcn_global_load_lds((const __attribute__((address_space(1))) void*)g,
                                   (__attribute__((address_space(3))) void*)l, 16, 0, 0);
}

// ---------------- taps (match numpy float64 _gauss1d) ----------------
__global__ void k_taps(float* __restrict__ taps) {
  if (threadIdx.x == 0 && blockIdx.x == 0) {
    {
      double k[5], s = 0.0;
      for (int i = 0; i < 5; i++) { double xv = (double)(i - 2) / 0.4; k[i] = exp(-0.5 * xv * xv); s += k[i]; }
      for (int i = 0; i < 5; i++) taps[i] = (float)(k[i] / s);
    }
    {
      double k[81], s = 0.0;
      for (int i = 0; i < 81; i++) { double xv = (double)(i - 40) / 10.0; k[i] = exp(-0.5 * xv * xv); s += k[i]; }
      for (int i = 0; i < 81; i++) taps[8 + i] = (float)(k[i] / s);
    }
  }
}

// ---------------- weight repack into MFMA B-fragment order, f16 split ----------------
// Bf (u32): chunk c (19): [c*3072 ..]: hi frags: t*256 + lane*4 + q ; lo at +1536
// B[k][n]: n = t*32 + (lane&31), k = 8*(lane>>5) + j, dword q holds j=2q (lo16), j=2q+1 (hi16)
// chunks: c<17: (ky=c, kx=k); c==17: (ky=k, kx=16); c==18: k==0 -> (ky=16,kx=16)
__global__ void k_repackB(const float* __restrict__ w, uint32_t* __restrict__ Bf) {
  int tid = blockIdx.x * 256 + threadIdx.x;
  if (tid >= 19 * 6 * 64 * 4) return;
  int q = tid & 3;
  int lane = (tid >> 2) & 63;
  int ct = tid >> 8;
  int t = ct % 6, c = ct / 6;
  int n = t * 32 + (lane & 31);
  int hf = lane >> 5;
  uint32_t hv = 0, lv = 0;
  for (int s = 0; s < 2; s++) {
    int j = 2 * q + s;
    int k = hf * 8 + j;   // 0..15
    float val = 0.f;
    if (n < NF) {
      if (c < 17)       val = w[n * 289 + c * 17 + k];
      else if (c == 17) val = w[n * 289 + k * 17 + 16];
      else if (k == 0)  val = w[n * 289 + 16 * 17 + 16];
    }
    val *= WSCALE;
    _Float16 hh = (_Float16)val;
    _Float16 ll = (_Float16)(val - (float)hh);
    hv |= (uint32_t)__builtin_bit_cast(uint16_t, hh) << (16 * s);
    lv |= (uint32_t)__builtin_bit_cast(uint16_t, ll) << (16 * s);
  }
  int base = c * 3072;
  int off = t * 256 + lane * 4 + q;
  Bf[base + off] = hv;
  Bf[base + 1536 + off] = lv;
}

// ---------------- gray ----------------
__global__ void k_gray(const float* __restrict__ x, float* __restrict__ gray) {
  int i = blockIdx.x * blockDim.x + threadIdx.x;
  if (i >= NB * NPIX) return;
  int b = i / NPIX, r = i % NPIX;
  const float* xb = x + (size_t)b * 3 * NPIX;
  gray[i] = 0.2989f * xb[r] + 0.587f * xb[NPIX + r] + 0.114f * xb[2 * NPIX + r];
}

// ---------------- vertical blur, both sigmas fused ----------------
__global__ void k_vblur2(const float* __restrict__ in, float* __restrict__ outA,
                         float* __restrict__ outB, const float* __restrict__ taps) {
  int i = blockIdx.x * blockDim.x + threadIdx.x;
  if (i >= NB * NPIX) return;
  int b = i / NPIX, r = i % NPIX;
  int y = r / W, xx = r % W;
  const float* img = in + (size_t)b * NPIX;
  float a = 0.f;
#pragma unroll
  for (int j = -2; j <= 2; j++) {
    int yy = y + j; yy = yy < 0 ? 0 : (yy > H - 1 ? H - 1 : yy);
    a = fmaf(taps[j + 2], img[yy * W + xx], a);
  }
  float c = 0.f;
  for (int j = -40; j <= 40; j++) {
    int yy = y + j; yy = yy < 0 ? 0 : (yy > H - 1 ? H - 1 : yy);
    c = fmaf(taps[8 + j + 40], img[yy * W + xx], c);
  }
  outA[i] = a;
  outB[i] = c;
}

// ---------------- horizontal blur + DoG + f16-split pack ----------------
__global__ void k_hblur_dog(const float* __restrict__ inA, const float* __restrict__ inB,
                            uint32_t* __restrict__ dogp, const float* __restrict__ taps) {
  int i = blockIdx.x * blockDim.x + threadIdx.x;
  if (i >= NB * NPIX) return;
  int b = i / NPIX, r = i % NPIX;
  int y = r / W, xx = r % W;
  const float* ra = inA + (size_t)b * NPIX + (size_t)y * W;
  const float* rb = inB + (size_t)b * NPIX + (size_t)y * W;
  float a = 0.f;
#pragma unroll
  for (int j = -2; j <= 2; j++) {
    int xc = xx + j; xc = xc < 0 ? 0 : (xc > W - 1 ? W - 1 : xc);
    a = fmaf(taps[j + 2], ra[xc], a);
  }
  float c = 0.f;
  for (int j = -40; j <= 40; j++) {
    int xc = xx + j; xc = xc < 0 ? 0 : (xc > W - 1 ? W - 1 : xc);
    c = fmaf(taps[8 + j + 40], rb[xc], c);
  }
  float d = a - c;
  _Float16 hh = (_Float16)d;
  _Float16 ll = (_Float16)(d - (float)hh);
  dogp[i] = ((uint32_t)__builtin_bit_cast(uint16_t, ll) << 16) |
            (uint32_t)__builtin_bit_cast(uint16_t, hh);
}

// ---------------- main: implicit-GEMM MFMA conv ----------------
// block: 256 thr = 4 waves; wave w = r*2+g: r = row (0..1), g = n-group (0..1)
// wave tile: M=64 px (2 m-tiles), N=96 (3 n-tiles), acc=96 VGPR -> 2 waves/SIMD.
// B: LDS, staged 3 K-chunks/phase, double-buffered; barrier once per 54 MFMA.
__launch_bounds__(256, 2)
__global__ void k_conv(const uint32_t* __restrict__ dogp,
                       const uint32_t* __restrict__ Bf,
                       const float* __restrict__ bins,
                       float* __restrict__ out) {
  __shared__ uint32_t pool[POOL_U32];

  const int b  = blockIdx.z;
  const int y0 = blockIdx.y * 2;
  const int x0 = blockIdx.x * 64;
  const int tid = threadIdx.x;
  const int lane = tid & 63;
  const int w  = __builtin_amdgcn_readfirstlane(tid >> 6);  // 0..3
  const int r  = w >> 1;        // row within block
  const int g  = w & 1;         // n-group (filters g*96 .. g*96+95)
  const int nl = lane & 31;
  const int half = lane >> 5;

  // ---- stage raw rows y0-8 .. y0+9, x0-8 .. x0+71 (zero-padded) ----
  const uint32_t* dgb = dogp + (size_t)b * NPIX;
  for (int i = tid; i < 18 * 80; i += 256) {
    int ry = i / 80, rx = i % 80;
    int gy = y0 + ry - 8, gx = x0 + rx - 8;
    uint32_t v = 0;
    if (gy >= 0 && gy < H && gx >= 0 && gx < W) v = dgb[gy * W + gx];
    pool[RAW_OFF + i] = v;
  }

  // ---- stage B phase 0 (chunks 0..2) into buffer 0 ----
  {
    const uint32_t* src = Bf + (size_t)tid * 4;
    uint32_t* dst = &pool[BB_OFF + tid * 4];
#pragma unroll
    for (int i = 0; i < 9; i++) gl_lds16(src + i * 1024, dst + i * 1024);
  }
  asm volatile("s_waitcnt vmcnt(0)" ::: "memory");
  __syncthreads();

  floatx16 acc[2][3];
#pragma unroll
  for (int mt = 0; mt < 2; mt++)
#pragma unroll
    for (int t = 0; t < 3; t++)
#pragma unroll
      for (int q = 0; q < 16; q++) acc[mt][t][q] = 0.f;

  int buf = 0;
  for (int p = 0; p < 7; p++) {
    const int c0 = p * 3;
    const int cnt = (c0 + 3 <= 19) ? 3 : (19 - c0);   // 3,3,3,3,3,3,1

    // issue next phase's staging into the other buffer
    const int n0 = c0 + 3;
    if (n0 < 19) {
      const int ncnt = (n0 + 3 <= 19) ? 3 : (19 - n0);
      const uint32_t* src = Bf + (size_t)n0 * BCH_U32 + (size_t)tid * 4;
      uint32_t* dst = &pool[BB_OFF + (buf ^ 1) * BUF_U32 + tid * 4];
      for (int i = 0; i < ncnt * 3; i++) gl_lds16(src + i * 1024, dst + i * 1024);
    }

    // compute the current phase's chunks (no barriers inside)
    for (int cc = 0; cc < cnt; cc++) {
      const int c = c0 + cc;

      // A fragments (hi & lo) for both m-tiles
      FragU fah[2], fal[2];
      if (c < 17) {
#pragma unroll
        for (int mt = 0; mt < 2; mt++) {
          const uint32_t* rp = &pool[RAW_OFF + (r + c) * 80 + mt * 32 + nl + half * 8];
          uint32_t d[8];
#pragma unroll
          for (int j = 0; j < 8; j++) d[j] = rp[j];
#pragma unroll
          for (int q = 0; q < 4; q++) {
            fah[mt].u[q] = __builtin_amdgcn_perm(d[2 * q + 1], d[2 * q], 0x05040100u);
            fal[mt].u[q] = __builtin_amdgcn_perm(d[2 * q + 1], d[2 * q], 0x07060302u);
          }
        }
      } else {
        int kyb = (c - 17) * 16 + half * 8;
#pragma unroll
        for (int mt = 0; mt < 2; mt++) {
          uint32_t d[8];
#pragma unroll
          for (int j = 0; j < 8; j++) {
            int ky = kyb + j; if (ky > 16) ky = 16;   // clamped reads killed by B=0
            d[j] = pool[RAW_OFF + (r + ky) * 80 + mt * 32 + nl + 16];
          }
#pragma unroll
          for (int q = 0; q < 4; q++) {
            fah[mt].u[q] = __builtin_amdgcn_perm(d[2 * q + 1], d[2 * q], 0x05040100u);
            fal[mt].u[q] = __builtin_amdgcn_perm(d[2 * q + 1], d[2 * q], 0x07060302u);
          }
        }
      }

      // B fragments from LDS (contiguous b128)
      FragU bh[3], bl[3];
#pragma unroll
      for (int t = 0; t < 3; t++) {
        int o = BB_OFF + buf * BUF_U32 + cc * BCH_U32 + g * 768 + t * 256 + lane * 4;
        bh[t].u = *(const u32x4*)&pool[o];
        bl[t].u = *(const u32x4*)&pool[o + 1536];
      }

      // MFMA, term-major: 6 independent dep-chains per term
#pragma unroll
      for (int t = 0; t < 3; t++)
#pragma unroll
        for (int mt = 0; mt < 2; mt++)
          acc[mt][t] = __builtin_amdgcn_mfma_f32_32x32x16_f16(fah[mt].h, bh[t].h, acc[mt][t], 0, 0, 0);
#pragma unroll
      for (int t = 0; t < 3; t++)
#pragma unroll
        for (int mt = 0; mt < 2; mt++)
          acc[mt][t] = __builtin_amdgcn_mfma_f32_32x32x16_f16(fal[mt].h, bh[t].h, acc[mt][t], 0, 0, 0);
#pragma unroll
      for (int t = 0; t < 3; t++)
#pragma unroll
        for (int mt = 0; mt < 2; mt++)
          acc[mt][t] = __builtin_amdgcn_mfma_f32_32x32x16_f16(fah[mt].h, bl[t].h, acc[mt][t], 0, 0, 0);
    }

    asm volatile("s_waitcnt vmcnt(0)" ::: "memory");
    __syncthreads();
    buf ^= 1;
  }

  // ---- epilogue (aliases dead raw region; last loop barrier protects) ----
  float* pm = (float*)&pool[0];     // [2][2][64]
  int*   pn = (int*)&pool[256];     // [2][2][64]
  float* pS = (float*)&pool[512];   // [2][2][64]
  float* pc = (float*)&pool[768];   // [2][2][64]
  int*   fn = (int*)&pool[1024];    // [2][64]
  float* fS = (float*)&pool[1152];  // [2][64]

  const float PI_F = 3.14159265358979323846f;

  // stage 1: per-wave partial argmax/sum over its 96 filters, per output pixel
#pragma unroll
  for (int mt = 0; mt < 2; mt++) {
#pragma unroll
    for (int q = 0; q < 16; q++) {
      float m = -1.f, S = 0.f;
      int bt = 0;
#pragma unroll
      for (int t = 0; t < 3; t++) {
        float v = fabsf(acc[mt][t][q]);
        S += v;
        if (v > m) { m = v; bt = t; }
      }
      int n = g * 96 + bt * 32 + nl;
#pragma unroll
      for (int msk = 1; msk < 32; msk <<= 1) {
        float vo = __shfl_xor(m, msk);
        int   no = __shfl_xor(n, msk);
        float So = __shfl_xor(S, msk);
        bool take = (vo > m) || (vo == m && no < n);
        m = take ? vo : m;
        n = take ? no : n;
        S += So;
      }
      if (nl == 0) {
        int px = mt * 32 + (q & 3) + 8 * (q >> 2) + 4 * half;
        pm[(r * 2 + g) * 64 + px] = m;
        pn[(r * 2 + g) * 64 + px] = n;
        pS[(r * 2 + g) * 64 + px] = S;
      }
    }
  }
  __syncthreads();

  // stage 2: g==0 waves combine n-groups, write orientation
  if (g == 0) {
    int p = lane;
    float m0 = pm[(r * 2 + 0) * 64 + p], m1 = pm[(r * 2 + 1) * 64 + p];
    int n = (m1 > m0) ? pn[(r * 2 + 1) * 64 + p] : pn[(r * 2 + 0) * 64 + p];
    float S = pS[(r * 2 + 0) * 64 + p] + pS[(r * 2 + 1) * 64 + p];
    fn[r * 64 + p] = n; fS[r * 64 + p] = S;
    float om = (float)n / 180.0f * 255.0f;
    out[(size_t)b * NPIX + (size_t)(y0 + r) * W + x0 + p] = om;
  }
  __syncthreads();

  // stage 3: per-wave partial confidence with the final winner
  {
    float bn[3];
#pragma unroll
    for (int t = 0; t < 3; t++) {
      int n = g * 96 + t * 32 + nl;
      bn[t] = (n < NF) ? bins[n] : 0.f;
    }
#pragma unroll
    for (int mt = 0; mt < 2; mt++) {
#pragma unroll
      for (int q = 0; q < 16; q++) {
        int px = mt * 32 + (q & 3) + 8 * (q >> 2) + 4 * half;
        int nwin = fn[r * 64 + px];
        float om = (float)nwin / 180.0f * 255.0f;
        float rad = om / 180.0f * PI_F;
        float C = 0.f;
#pragma unroll
        for (int t = 0; t < 3; t++) {
          float dd = rad - bn[t];
          float d0 = fabsf(dd);
          float d1 = fabsf(dd - PI_F);
          float d2 = fabsf(dd + PI_F);
          float d = fminf(d0, fminf(d1, d2));
          C = fmaf(d * d, fabsf(acc[mt][t][q]), C);
        }
#pragma unroll
        for (int msk = 1; msk < 32; msk <<= 1) C += __shfl_xor(C, msk);
        if (nl == 0) pc[(r * 2 + g) * 64 + px] = C;
      }
    }
  }
  __syncthreads();

  // stage 4: g==0 waves finalize confidence
  if (g == 0) {
    int p = lane;
    float C = pc[(r * 2 + 0) * 64 + p] + pc[(r * 2 + 1) * 64 + p];
    out[(size_t)NB * NPIX + (size_t)b * NPIX + (size_t)(y0 + r) * W + x0 + p] = C / fS[r * 64 + p];
  }
}

extern "C" void kernel_launch(void* const* d_in, const int* in_sizes, int n_in,
                              void* d_out, int out_size, void* d_ws, size_t ws_size,
                              hipStream_t stream) {
  const float* x = (const float*)d_in[0];      // [2,3,512,512]
  const float* wts = (const float*)d_in[1];    // [180,1,17,17]
  const float* bins = (const float*)d_in[2];   // [180]
  float* out = (float*)d_out;

  float* ws = (float*)d_ws;
  float* gray = ws;                                 // 524288 f32
  float* tmpA = ws + (size_t)NB * NPIX;             // 524288 f32
  float* tmpB = tmpA + (size_t)NB * NPIX;           // 524288 f32
  uint32_t* dogp = (uint32_t*)(tmpB + (size_t)NB * NPIX);  // 524288 u32
  float* taps = (float*)(dogp + (size_t)NB * NPIX); // 128 f32
  uint32_t* Bf = (uint32_t*)(taps + 128);           // 19*3072 u32

  k_taps<<<1, 64, 0, stream>>>(taps);
  k_repackB<<<114, 256, 0, stream>>>(wts, Bf);

  int n = NB * NPIX;
  int blk = 256, grd = (n + blk - 1) / blk;
  k_gray<<<grd, blk, 0, stream>>>(x, gray);
  k_vblur2<<<grd, blk, 0, stream>>>(gray, tmpA, tmpB, taps);
  k_hblur_dog<<<grd, blk, 0, stream>>>(tmpA, tmpB, dogp, taps);

  dim3 g(W / 64, H / 2, NB);
  k_conv<<<g, 256, 0, stream>>>(dogp, Bf, bins, out);
}

// Round 8
// 241.463 us; speedup vs baseline: 1.4706x; 1.4706x over previous
//
#include <hip/hip_runtime.h>
#include <math.h>
#include <stdint.h>

#define H 512
#define W 512
#define NPIX (H * W)          // 262144
#define NB 2
#define NF 180
#define KS 17
#define WSCALE 1024.0f        // exact power of two; cancels in both outputs

// LDS pool (u32): raw rows 20*80=1600; B double buffer 2 phases * 2 chunks * 3072
#define RAW_OFF 0
#define BB_OFF  1600
#define BCH_U32 3072          // one K-chunk of B (hi+lo, N=192), 12 KB
#define PH_U32  (2 * BCH_U32) // 2-chunk phase buffer, 24 KB
#define POOL_U32 (1600 + 2 * PH_U32)   // 13888 u32 = 55.5 KB -> 2 blocks/CU

typedef _Float16 half8 __attribute__((ext_vector_type(8)));
typedef float floatx16 __attribute__((ext_vector_type(16)));
typedef uint32_t u32x4 __attribute__((ext_vector_type(4)));

union FragU { u32x4 u; half8 h; };

__device__ inline void gl_lds16(const uint32_t* g, uint32_t* l) {
  __builtin_amdgcn_global_load_lds((const __attribute__((address_space(1))) void*)g,
                                   (__attribute__((address_space(3))) void*)l, 16, 0, 0);
}

// ---------------- taps (match numpy float64 _gauss1d) ----------------
__global__ void k_taps(float* __restrict__ taps) {
  if (threadIdx.x == 0 && blockIdx.x == 0) {
    {
      double k[5], s = 0.0;
      for (int i = 0; i < 5; i++) { double xv = (double)(i - 2) / 0.4; k[i] = exp(-0.5 * xv * xv); s += k[i]; }
      for (int i = 0; i < 5; i++) taps[i] = (float)(k[i] / s);
    }
    {
      double k[81], s = 0.0;
      for (int i = 0; i < 81; i++) { double xv = (double)(i - 40) / 10.0; k[i] = exp(-0.5 * xv * xv); s += k[i]; }
      for (int i = 0; i < 81; i++) taps[8 + i] = (float)(k[i] / s);
    }
  }
}

// ---------------- weight repack into MFMA B-fragment order, f16 split ----------------
// Bf (u32): chunk c (19): [c*3072 ..]: hi frags: t*256 + lane*4 + q ; lo at +1536
// B[k][n]: n = t*32 + (lane&31), k = 8*(lane>>5) + j, dword q holds j=2q (lo16), j=2q+1 (hi16)
// chunks: c<17: (ky=c, kx=k); c==17: (ky=k, kx=16); c==18: k==0 -> (ky=16,kx=16)
__global__ void k_repackB(const float* __restrict__ w, uint32_t* __restrict__ Bf) {
  int tid = blockIdx.x * 256 + threadIdx.x;
  if (tid >= 19 * 6 * 64 * 4) return;
  int q = tid & 3;
  int lane = (tid >> 2) & 63;
  int ct = tid >> 8;
  int t = ct % 6, c = ct / 6;
  int n = t * 32 + (lane & 31);
  int hf = lane >> 5;
  uint32_t hv = 0, lv = 0;
  for (int s = 0; s < 2; s++) {
    int j = 2 * q + s;
    int k = hf * 8 + j;   // 0..15
    float val = 0.f;
    if (n < NF) {
      if (c < 17)       val = w[n * 289 + c * 17 + k];
      else if (c == 17) val = w[n * 289 + k * 17 + 16];
      else if (k == 0)  val = w[n * 289 + 16 * 17 + 16];
    }
    val *= WSCALE;
    _Float16 hh = (_Float16)val;
    _Float16 ll = (_Float16)(val - (float)hh);
    hv |= (uint32_t)__builtin_bit_cast(uint16_t, hh) << (16 * s);
    lv |= (uint32_t)__builtin_bit_cast(uint16_t, ll) << (16 * s);
  }
  int base = c * 3072;
  int off = t * 256 + lane * 4 + q;
  Bf[base + off] = hv;
  Bf[base + 1536 + off] = lv;
}

// ---------------- gray ----------------
__global__ void k_gray(const float* __restrict__ x, float* __restrict__ gray) {
  int i = blockIdx.x * blockDim.x + threadIdx.x;
  if (i >= NB * NPIX) return;
  int b = i / NPIX, r = i % NPIX;
  const float* xb = x + (size_t)b * 3 * NPIX;
  gray[i] = 0.2989f * xb[r] + 0.587f * xb[NPIX + r] + 0.114f * xb[2 * NPIX + r];
}

// ---------------- vertical blur, both sigmas fused ----------------
__global__ void k_vblur2(const float* __restrict__ in, float* __restrict__ outA,
                         float* __restrict__ outB, const float* __restrict__ taps) {
  int i = blockIdx.x * blockDim.x + threadIdx.x;
  if (i >= NB * NPIX) return;
  int b = i / NPIX, r = i % NPIX;
  int y = r / W, xx = r % W;
  const float* img = in + (size_t)b * NPIX;
  float a = 0.f;
#pragma unroll
  for (int j = -2; j <= 2; j++) {
    int yy = y + j; yy = yy < 0 ? 0 : (yy > H - 1 ? H - 1 : yy);
    a = fmaf(taps[j + 2], img[yy * W + xx], a);
  }
  float c = 0.f;
  for (int j = -40; j <= 40; j++) {
    int yy = y + j; yy = yy < 0 ? 0 : (yy > H - 1 ? H - 1 : yy);
    c = fmaf(taps[8 + j + 40], img[yy * W + xx], c);
  }
  outA[i] = a;
  outB[i] = c;
}

// ---------------- horizontal blur + DoG + f16-split pack ----------------
__global__ void k_hblur_dog(const float* __restrict__ inA, const float* __restrict__ inB,
                            uint32_t* __restrict__ dogp, const float* __restrict__ taps) {
  int i = blockIdx.x * blockDim.x + threadIdx.x;
  if (i >= NB * NPIX) return;
  int b = i / NPIX, r = i % NPIX;
  int y = r / W, xx = r % W;
  const float* ra = inA + (size_t)b * NPIX + (size_t)y * W;
  const float* rb = inB + (size_t)b * NPIX + (size_t)y * W;
  float a = 0.f;
#pragma unroll
  for (int j = -2; j <= 2; j++) {
    int xc = xx + j; xc = xc < 0 ? 0 : (xc > W - 1 ? W - 1 : xc);
    a = fmaf(taps[j + 2], ra[xc], a);
  }
  float c = 0.f;
  for (int j = -40; j <= 40; j++) {
    int xc = xx + j; xc = xc < 0 ? 0 : (xc > W - 1 ? W - 1 : xc);
    c = fmaf(taps[8 + j + 40], rb[xc], c);
  }
  float d = a - c;
  _Float16 hh = (_Float16)d;
  _Float16 ll = (_Float16)(d - (float)hh);
  dogp[i] = ((uint32_t)__builtin_bit_cast(uint16_t, ll) << 16) |
            (uint32_t)__builtin_bit_cast(uint16_t, hh);
}

// ---------------- main: implicit-GEMM MFMA conv ----------------
// block: 256 thr = 4 waves; wave w: rp=w>>1 (row pair), ch=w&1 (col half)
// wave tile: M = 2 rows x 32 cols (2 m-tiles, A-frag ROLLS across chunks),
// N = 192 (6 n-tiles), acc = 192 VGPR. B: LDS, 2 chunks/phase double-buffered.
__launch_bounds__(256, 2)
__global__ void k_conv(const uint32_t* __restrict__ dogp,
                       const uint32_t* __restrict__ Bf,
                       const float* __restrict__ bins,
                       float* __restrict__ out) {
  __shared__ uint32_t pool[POOL_U32];

  const int b  = blockIdx.z;
  const int y0 = blockIdx.y * 4;
  const int x0 = blockIdx.x * 64;
  const int tid = threadIdx.x;
  const int lane = tid & 63;
  const int w  = __builtin_amdgcn_readfirstlane(tid >> 6);  // 0..3
  const int rp2 = (w >> 1) * 2;   // 0 or 2: wave's row-pair base
  const int ch  = w & 1;          // col half (0: cols 0..31, 1: 32..63)
  const int nl = lane & 31;
  const int half = lane >> 5;

  // ---- stage raw rows y0-8 .. y0+11 (20), cols x0-8 .. x0+71 (zero-padded) ----
  const uint32_t* dgb = dogp + (size_t)b * NPIX;
  for (int i = tid; i < 20 * 80; i += 256) {
    int ry = i / 80, rx = i % 80;
    int gy = y0 + ry - 8, gx = x0 + rx - 8;
    uint32_t v = 0;
    if (gy >= 0 && gy < H && gx >= 0 && gx < W) v = dgb[gy * W + gx];
    pool[RAW_OFF + i] = v;
  }
  // ---- stage B chunks 0,1 into phase buffer 0 ----
  {
    const uint32_t* src = Bf + (size_t)tid * 4;
    uint32_t* dst = &pool[BB_OFF + tid * 4];
#pragma unroll
    for (int i = 0; i < 6; i++) gl_lds16(src + i * 1024, dst + i * 1024);
  }
  asm volatile("s_waitcnt vmcnt(0)" ::: "memory");
  __syncthreads();

  floatx16 acc[2][6];
#pragma unroll
  for (int mt = 0; mt < 2; mt++)
#pragma unroll
    for (int t = 0; t < 6; t++)
#pragma unroll
      for (int q = 0; q < 16; q++) acc[mt][t][q] = 0.f;

  const int abase = ch * 32 + nl + half * 8;

  // build A row fragment (hi/lo) for tile row tr
  auto buildRow = [&](int tr, FragU& fh, FragU& fl) {
    const uint32_t* rp = &pool[RAW_OFF + tr * 80 + abase];
    uint32_t d[8];
#pragma unroll
    for (int j = 0; j < 8; j++) d[j] = rp[j];
#pragma unroll
    for (int q = 0; q < 4; q++) {
      fh.u[q] = __builtin_amdgcn_perm(d[2 * q + 1], d[2 * q], 0x05040100u);
      fl.u[q] = __builtin_amdgcn_perm(d[2 * q + 1], d[2 * q], 0x07060302u);
    }
  };
  // build A strip fragment for tail chunk c (17/18), m-tile row base rb
  auto buildStrip = [&](int c, int rb, FragU& fh, FragU& fl) {
    int kyb = (c - 17) * 16 + half * 8;
    uint32_t d[8];
#pragma unroll
    for (int j = 0; j < 8; j++) {
      int ky = kyb + j; if (ky > 16) ky = 16;   // clamped reads killed by B=0
      d[j] = pool[RAW_OFF + (rb + ky) * 80 + ch * 32 + nl + 16];
    }
#pragma unroll
    for (int q = 0; q < 4; q++) {
      fh.u[q] = __builtin_amdgcn_perm(d[2 * q + 1], d[2 * q], 0x05040100u);
      fl.u[q] = __builtin_amdgcn_perm(d[2 * q + 1], d[2 * q], 0x07060302u);
    }
  };
  auto readB = [&](int off, FragU* bh, FragU* bl) {
#pragma unroll
    for (int t = 0; t < 6; t++) {
      bh[t].u = *(const u32x4*)&pool[off + t * 256 + lane * 4];
      bl[t].u = *(const u32x4*)&pool[off + 1536 + t * 256 + lane * 4];
    }
  };
  auto mfmaChunk = [&](FragU& a0h, FragU& a0l, FragU& a1h, FragU& a1l,
                       FragU* bh, FragU* bl) {
#pragma unroll
    for (int t = 0; t < 6; t++) {
      acc[0][t] = __builtin_amdgcn_mfma_f32_32x32x16_f16(a0h.h, bh[t].h, acc[0][t], 0, 0, 0);
      acc[1][t] = __builtin_amdgcn_mfma_f32_32x32x16_f16(a1h.h, bh[t].h, acc[1][t], 0, 0, 0);
    }
#pragma unroll
    for (int t = 0; t < 6; t++) {
      acc[0][t] = __builtin_amdgcn_mfma_f32_32x32x16_f16(a0l.h, bh[t].h, acc[0][t], 0, 0, 0);
      acc[1][t] = __builtin_amdgcn_mfma_f32_32x32x16_f16(a1l.h, bh[t].h, acc[1][t], 0, 0, 0);
    }
#pragma unroll
    for (int t = 0; t < 6; t++) {
      acc[0][t] = __builtin_amdgcn_mfma_f32_32x32x16_f16(a0h.h, bl[t].h, acc[0][t], 0, 0, 0);
      acc[1][t] = __builtin_amdgcn_mfma_f32_32x32x16_f16(a1h.h, bl[t].h, acc[1][t], 0, 0, 0);
    }
  };

  FragU a0h, a0l, a1h, a1l;
  buildRow(rp2, a0h, a0l);   // chunk 0, m-tile 0 (rolls forward)

  int buf = 0;
  for (int p = 0; p < 8; p++) {          // chunks 2p, 2p+1 (c <= 15, row-type)
    // stage chunks 2p+2, 2p+3 into the other phase buffer
    {
      const uint32_t* src = Bf + (size_t)(2 * p + 2) * BCH_U32 + (size_t)tid * 4;
      uint32_t* dst = &pool[BB_OFF + (buf ^ 1) * PH_U32 + tid * 4];
#pragma unroll
      for (int i = 0; i < 6; i++) gl_lds16(src + i * 1024, dst + i * 1024);
    }
    FragU bh[6], bl[6];
    // chunk c0 = 2p
    buildRow(rp2 + 1 + 2 * p, a1h, a1l);
    readB(BB_OFF + buf * PH_U32, bh, bl);
    mfmaChunk(a0h, a0l, a1h, a1l, bh, bl);
    a0h = a1h; a0l = a1l;
    // chunk c1 = 2p+1
    buildRow(rp2 + 2 + 2 * p, a1h, a1l);
    readB(BB_OFF + buf * PH_U32 + BCH_U32, bh, bl);
    mfmaChunk(a0h, a0l, a1h, a1l, bh, bl);
    a0h = a1h; a0l = a1l;

    asm volatile("s_waitcnt vmcnt(0)" ::: "memory");
    __syncthreads();
    buf ^= 1;
  }

  // phase 8: chunks 16 (row-type, rolled) and 17 (strip); stage chunk 18
  {
    const uint32_t* src = Bf + (size_t)18 * BCH_U32 + (size_t)tid * 4;
    uint32_t* dst = &pool[BB_OFF + (buf ^ 1) * PH_U32 + tid * 4];
#pragma unroll
    for (int i = 0; i < 3; i++) gl_lds16(src + i * 1024, dst + i * 1024);

    FragU bh[6], bl[6];
    buildRow(rp2 + 17, a1h, a1l);                   // c=16, m-tile 1
    readB(BB_OFF + buf * PH_U32, bh, bl);
    mfmaChunk(a0h, a0l, a1h, a1l, bh, bl);

    FragU s0h, s0l, s1h, s1l;
    buildStrip(17, rp2, s0h, s0l);
    buildStrip(17, rp2 + 1, s1h, s1l);
    readB(BB_OFF + buf * PH_U32 + BCH_U32, bh, bl);
    mfmaChunk(s0h, s0l, s1h, s1l, bh, bl);

    asm volatile("s_waitcnt vmcnt(0)" ::: "memory");
    __syncthreads();
    buf ^= 1;
  }
  // phase 9: chunk 18 (strip), no staging, no barrier
  {
    FragU bh[6], bl[6];
    FragU s0h, s0l, s1h, s1l;
    buildStrip(18, rp2, s0h, s0l);
    buildStrip(18, rp2 + 1, s1h, s1l);
    readB(BB_OFF + buf * PH_U32, bh, bl);
    mfmaChunk(s0h, s0l, s1h, s1l, bh, bl);
  }

  // ---- fully in-register epilogue (wave owns all 192 filters for its pixels) ----
  const float PI_F = 3.14159265358979323846f;
  float bn[6];
#pragma unroll
  for (int t = 0; t < 6; t++) {
    int n = t * 32 + nl;
    bn[t] = (n < NF) ? bins[n] : 0.f;
  }

#pragma unroll
  for (int mt = 0; mt < 2; mt++) {
#pragma unroll
    for (int q = 0; q < 16; q++) {
      float v[6];
      float S = 0.f, m = -1.f;
      int bt = 0;
#pragma unroll
      for (int t = 0; t < 6; t++) {
        v[t] = fabsf(acc[mt][t][q]);
        S += v[t];
        if (v[t] > m) { m = v[t]; bt = t; }   // first-max within lane (n ascending with t)
      }
      int n = bt * 32 + nl;
      // butterfly over the 32-lane n-group (argmax, smaller-index tie-break; sum)
#pragma unroll
      for (int msk = 1; msk < 32; msk <<= 1) {
        float vo = __shfl_xor(m, msk);
        int   no = __shfl_xor(n, msk);
        float So = __shfl_xor(S, msk);
        bool take = (vo > m) || (vo == m && no < n);
        m = take ? vo : m;
        n = take ? no : n;
        S += So;
      }
      float om  = (float)n / 180.0f * 255.0f;
      float rad = om / 180.0f * PI_F;
      float C = 0.f;
#pragma unroll
      for (int t = 0; t < 6; t++) {
        float dd = rad - bn[t];
        float d0 = fabsf(dd);
        float d1 = fabsf(dd - PI_F);
        float d2 = fabsf(dd + PI_F);
        float d = fminf(d0, fminf(d1, d2));
        C = fmaf(d * d, v[t], C);
      }
#pragma unroll
      for (int msk = 1; msk < 32; msk <<= 1) C += __shfl_xor(C, msk);
      if (nl == 0) {
        int y = y0 + rp2 + mt;
        int x = x0 + ch * 32 + (q & 3) + 8 * (q >> 2) + 4 * half;
        out[(size_t)b * NPIX + (size_t)y * W + x] = om;
        out[(size_t)NB * NPIX + (size_t)b * NPIX + (size_t)y * W + x] = C / S;
      }
    }
  }
}

extern "C" void kernel_launch(void* const* d_in, const int* in_sizes, int n_in,
                              void* d_out, int out_size, void* d_ws, size_t ws_size,
                              hipStream_t stream) {
  const float* x = (const float*)d_in[0];      // [2,3,512,512]
  const float* wts = (const float*)d_in[1];    // [180,1,17,17]
  const float* bins = (const float*)d_in[2];   // [180]
  float* out = (float*)d_out;

  float* ws = (float*)d_ws;
  float* gray = ws;                                 // 524288 f32
  float* tmpA = ws + (size_t)NB * NPIX;             // 524288 f32
  float* tmpB = tmpA + (size_t)NB * NPIX;           // 524288 f32
  uint32_t* dogp = (uint32_t*)(tmpB + (size_t)NB * NPIX);  // 524288 u32
  float* taps = (float*)(dogp + (size_t)NB * NPIX); // 128 f32
  uint32_t* Bf = (uint32_t*)(taps + 128);           // 19*3072 u32

  k_taps<<<1, 64, 0, stream>>>(taps);
  k_repackB<<<114, 256, 0, stream>>>(wts, Bf);

  int n = NB * NPIX;
  int blk = 256, grd = (n + blk - 1) / blk;
  k_gray<<<grd, blk, 0, stream>>>(x, gray);
  k_vblur2<<<grd, blk, 0, stream>>>(gray, tmpA, tmpB, taps);
  k_hblur_dog<<<grd, blk, 0, stream>>>(tmpA, tmpB, dogp, taps);

  dim3 g(W / 64, H / 4, NB);
  k_conv<<<g, 256, 0, stream>>>(dogp, Bf, bins, out);
}

// Round 9
// 240.240 us; speedup vs baseline: 1.4781x; 1.0051x over previous
//
#include <hip/hip_runtime.h>
#include <math.h>
#include <stdint.h>

#define H 512
#define W 512
#define NPIX (H * W)          // 262144
#define NB 2
#define NF 180
#define KS 17
#define WSCALE 1024.0f        // exact power of two; cancels in both outputs

// LDS pool (u32): raw rows 20*80=1600; B double buffer 2 phases * 2 chunks * 3072
#define RAW_OFF 0
#define BB_OFF  1600
#define BCH_U32 3072          // one K-chunk of B (hi+lo, N=192), 12 KB
#define PH_U32  (2 * BCH_U32) // 2-chunk phase buffer, 24 KB
#define POOL_U32 (1600 + 2 * PH_U32)   // 13888 u32 = 55.5 KB -> 2 blocks/CU

typedef _Float16 half8 __attribute__((ext_vector_type(8)));
typedef float floatx16 __attribute__((ext_vector_type(16)));
typedef uint32_t u32x4 __attribute__((ext_vector_type(4)));

union FragU { u32x4 u; half8 h; };

__device__ inline void gl_lds16(const uint32_t* g, uint32_t* l) {
  __builtin_amdgcn_global_load_lds((const __attribute__((address_space(1))) void*)g,
                                   (__attribute__((address_space(3))) void*)l, 16, 0, 0);
}

// ---------------- taps (match numpy float64 _gauss1d) ----------------
__global__ void k_taps(float* __restrict__ taps) {
  if (threadIdx.x == 0 && blockIdx.x == 0) {
    {
      double k[5], s = 0.0;
      for (int i = 0; i < 5; i++) { double xv = (double)(i - 2) / 0.4; k[i] = exp(-0.5 * xv * xv); s += k[i]; }
      for (int i = 0; i < 5; i++) taps[i] = (float)(k[i] / s);
    }
    {
      double k[81], s = 0.0;
      for (int i = 0; i < 81; i++) { double xv = (double)(i - 40) / 10.0; k[i] = exp(-0.5 * xv * xv); s += k[i]; }
      for (int i = 0; i < 81; i++) taps[8 + i] = (float)(k[i] / s);
    }
  }
}

// ---------------- weight repack into MFMA B-fragment order, f16 split ----------------
// Bf (u32): chunk c (19): [c*3072 ..]: hi frags: t*256 + lane*4 + q ; lo at +1536
// B[k][n]: n = t*32 + (lane&31), k = 8*(lane>>5) + j, dword q holds j=2q (lo16), j=2q+1 (hi16)
// chunks: c<17: (ky=c, kx=k); c==17: (ky=k, kx=16); c==18: k==0 -> (ky=16,kx=16)
__global__ void k_repackB(const float* __restrict__ w, uint32_t* __restrict__ Bf) {
  int tid = blockIdx.x * 256 + threadIdx.x;
  if (tid >= 19 * 6 * 64 * 4) return;
  int q = tid & 3;
  int lane = (tid >> 2) & 63;
  int ct = tid >> 8;
  int t = ct % 6, c = ct / 6;
  int n = t * 32 + (lane & 31);
  int hf = lane >> 5;
  uint32_t hv = 0, lv = 0;
  for (int s = 0; s < 2; s++) {
    int j = 2 * q + s;
    int k = hf * 8 + j;   // 0..15
    float val = 0.f;
    if (n < NF) {
      if (c < 17)       val = w[n * 289 + c * 17 + k];
      else if (c == 17) val = w[n * 289 + k * 17 + 16];
      else if (k == 0)  val = w[n * 289 + 16 * 17 + 16];
    }
    val *= WSCALE;
    _Float16 hh = (_Float16)val;
    _Float16 ll = (_Float16)(val - (float)hh);
    hv |= (uint32_t)__builtin_bit_cast(uint16_t, hh) << (16 * s);
    lv |= (uint32_t)__builtin_bit_cast(uint16_t, ll) << (16 * s);
  }
  int base = c * 3072;
  int off = t * 256 + lane * 4 + q;
  Bf[base + off] = hv;
  Bf[base + 1536 + off] = lv;
}

// ---------------- gray ----------------
__global__ void k_gray(const float* __restrict__ x, float* __restrict__ gray) {
  int i = blockIdx.x * blockDim.x + threadIdx.x;
  if (i >= NB * NPIX) return;
  int b = i / NPIX, r = i % NPIX;
  const float* xb = x + (size_t)b * 3 * NPIX;
  gray[i] = 0.2989f * xb[r] + 0.587f * xb[NPIX + r] + 0.114f * xb[2 * NPIX + r];
}

// ---------------- vertical blur, both sigmas fused ----------------
__global__ void k_vblur2(const float* __restrict__ in, float* __restrict__ outA,
                         float* __restrict__ outB, const float* __restrict__ taps) {
  int i = blockIdx.x * blockDim.x + threadIdx.x;
  if (i >= NB * NPIX) return;
  int b = i / NPIX, r = i % NPIX;
  int y = r / W, xx = r % W;
  const float* img = in + (size_t)b * NPIX;
  float a = 0.f;
#pragma unroll
  for (int j = -2; j <= 2; j++) {
    int yy = y + j; yy = yy < 0 ? 0 : (yy > H - 1 ? H - 1 : yy);
    a = fmaf(taps[j + 2], img[yy * W + xx], a);
  }
  float c = 0.f;
  for (int j = -40; j <= 40; j++) {
    int yy = y + j; yy = yy < 0 ? 0 : (yy > H - 1 ? H - 1 : yy);
    c = fmaf(taps[8 + j + 40], img[yy * W + xx], c);
  }
  outA[i] = a;
  outB[i] = c;
}

// ---------------- horizontal blur + DoG + f16-split pack ----------------
__global__ void k_hblur_dog(const float* __restrict__ inA, const float* __restrict__ inB,
                            uint32_t* __restrict__ dogp, const float* __restrict__ taps) {
  int i = blockIdx.x * blockDim.x + threadIdx.x;
  if (i >= NB * NPIX) return;
  int b = i / NPIX, r = i % NPIX;
  int y = r / W, xx = r % W;
  const float* ra = inA + (size_t)b * NPIX + (size_t)y * W;
  const float* rb = inB + (size_t)b * NPIX + (size_t)y * W;
  float a = 0.f;
#pragma unroll
  for (int j = -2; j <= 2; j++) {
    int xc = xx + j; xc = xc < 0 ? 0 : (xc > W - 1 ? W - 1 : xc);
    a = fmaf(taps[j + 2], ra[xc], a);
  }
  float c = 0.f;
  for (int j = -40; j <= 40; j++) {
    int xc = xx + j; xc = xc < 0 ? 0 : (xc > W - 1 ? W - 1 : xc);
    c = fmaf(taps[8 + j + 40], rb[xc], c);
  }
  float d = a - c;
  _Float16 hh = (_Float16)d;
  _Float16 ll = (_Float16)(d - (float)hh);
  dogp[i] = ((uint32_t)__builtin_bit_cast(uint16_t, ll) << 16) |
            (uint32_t)__builtin_bit_cast(uint16_t, hh);
}

// ---------------- main: implicit-GEMM MFMA conv ----------------
// 1-D grid 2048, XCD-swizzled: bid=(nid&7)*256+(nid>>3); bid -> (bz, bx, by)
// block: 256 thr = 4 waves; wave w: rp=w>>1 (row pair), ch=w&1 (col half)
// wave tile: M = 2 rows x 32 cols (A-frag ROLLS across chunks), N = 192 (6 n-tiles).
// B: LDS, 2 chunks/phase double-buffered, read 3 n-tiles at a time (T4-lite);
// s_setprio(1) around each 18-MFMA cluster (T5).
__launch_bounds__(256, 2)
__global__ void k_conv(const uint32_t* __restrict__ dogp,
                       const uint32_t* __restrict__ Bf,
                       const float* __restrict__ bins,
                       float* __restrict__ out) {
  __shared__ uint32_t pool[POOL_U32];

  const int nid = blockIdx.x;
  const int bid = (nid & 7) * 256 + (nid >> 3);   // bijective XCD swizzle (2048 = 8*256)
  const int bz = bid >> 10;          // batch
  const int rem = bid & 1023;
  const int bx = rem >> 7;           // 0..7
  const int by = rem & 127;          // 0..127 (consecutive within an XCD chunk)

  const int b  = bz;
  const int y0 = by * 4;
  const int x0 = bx * 64;
  const int tid = threadIdx.x;
  const int lane = tid & 63;
  const int w  = __builtin_amdgcn_readfirstlane(tid >> 6);  // 0..3
  const int rp2 = (w >> 1) * 2;   // 0 or 2: wave's row-pair base
  const int ch  = w & 1;          // col half (0: cols 0..31, 1: 32..63)
  const int nl = lane & 31;
  const int half = lane >> 5;

  // ---- stage raw rows y0-8 .. y0+11 (20), cols x0-8 .. x0+71 (zero-padded) ----
  const uint32_t* dgb = dogp + (size_t)b * NPIX;
  for (int i = tid; i < 20 * 80; i += 256) {
    int ry = i / 80, rx = i % 80;
    int gy = y0 + ry - 8, gx = x0 + rx - 8;
    uint32_t v = 0;
    if (gy >= 0 && gy < H && gx >= 0 && gx < W) v = dgb[gy * W + gx];
    pool[RAW_OFF + i] = v;
  }
  // ---- stage B chunks 0,1 into phase buffer 0 ----
  {
    const uint32_t* src = Bf + (size_t)tid * 4;
    uint32_t* dst = &pool[BB_OFF + tid * 4];
#pragma unroll
    for (int i = 0; i < 6; i++) gl_lds16(src + i * 1024, dst + i * 1024);
  }
  asm volatile("s_waitcnt vmcnt(0)" ::: "memory");
  __syncthreads();

  floatx16 acc[2][6];
#pragma unroll
  for (int mt = 0; mt < 2; mt++)
#pragma unroll
    for (int t = 0; t < 6; t++)
#pragma unroll
      for (int q = 0; q < 16; q++) acc[mt][t][q] = 0.f;

  const int abase = ch * 32 + nl + half * 8;

  // build A row fragment (hi/lo) for tile row tr
  auto buildRow = [&](int tr, FragU& fh, FragU& fl) {
    const uint32_t* rp = &pool[RAW_OFF + tr * 80 + abase];
    uint32_t d[8];
#pragma unroll
    for (int j = 0; j < 8; j++) d[j] = rp[j];
#pragma unroll
    for (int q = 0; q < 4; q++) {
      fh.u[q] = __builtin_amdgcn_perm(d[2 * q + 1], d[2 * q], 0x05040100u);
      fl.u[q] = __builtin_amdgcn_perm(d[2 * q + 1], d[2 * q], 0x07060302u);
    }
  };
  // build A strip fragment for tail chunk c (17/18), m-tile row base rb
  auto buildStrip = [&](int c, int rb, FragU& fh, FragU& fl) {
    int kyb = (c - 17) * 16 + half * 8;
    uint32_t d[8];
#pragma unroll
    for (int j = 0; j < 8; j++) {
      int ky = kyb + j; if (ky > 16) ky = 16;   // clamped reads killed by B=0
      d[j] = pool[RAW_OFF + (rb + ky) * 80 + ch * 32 + nl + 16];
    }
#pragma unroll
    for (int q = 0; q < 4; q++) {
      fh.u[q] = __builtin_amdgcn_perm(d[2 * q + 1], d[2 * q], 0x05040100u);
      fl.u[q] = __builtin_amdgcn_perm(d[2 * q + 1], d[2 * q], 0x07060302u);
    }
  };
  // half-chunk: read 3 n-tiles of B, 18 MFMAs under setprio
  auto halfChunk = [&](int off, int t0, FragU& a0h, FragU& a0l, FragU& a1h, FragU& a1l) {
    FragU bh[3], bl[3];
#pragma unroll
    for (int t = 0; t < 3; t++) {
      bh[t].u = *(const u32x4*)&pool[off + (t0 + t) * 256 + lane * 4];
      bl[t].u = *(const u32x4*)&pool[off + 1536 + (t0 + t) * 256 + lane * 4];
    }
    __builtin_amdgcn_s_setprio(1);
#pragma unroll
    for (int t = 0; t < 3; t++) {
      acc[0][t0 + t] = __builtin_amdgcn_mfma_f32_32x32x16_f16(a0h.h, bh[t].h, acc[0][t0 + t], 0, 0, 0);
      acc[1][t0 + t] = __builtin_amdgcn_mfma_f32_32x32x16_f16(a1h.h, bh[t].h, acc[1][t0 + t], 0, 0, 0);
    }
#pragma unroll
    for (int t = 0; t < 3; t++) {
      acc[0][t0 + t] = __builtin_amdgcn_mfma_f32_32x32x16_f16(a0l.h, bh[t].h, acc[0][t0 + t], 0, 0, 0);
      acc[1][t0 + t] = __builtin_amdgcn_mfma_f32_32x32x16_f16(a1l.h, bh[t].h, acc[1][t0 + t], 0, 0, 0);
    }
#pragma unroll
    for (int t = 0; t < 3; t++) {
      acc[0][t0 + t] = __builtin_amdgcn_mfma_f32_32x32x16_f16(a0h.h, bl[t].h, acc[0][t0 + t], 0, 0, 0);
      acc[1][t0 + t] = __builtin_amdgcn_mfma_f32_32x32x16_f16(a1h.h, bl[t].h, acc[1][t0 + t], 0, 0, 0);
    }
    __builtin_amdgcn_s_setprio(0);
  };
  auto doChunk = [&](int off, FragU& a0h, FragU& a0l, FragU& a1h, FragU& a1l) {
    halfChunk(off, 0, a0h, a0l, a1h, a1l);
    halfChunk(off, 3, a0h, a0l, a1h, a1l);
  };

  FragU a0h, a0l, a1h, a1l;
  buildRow(rp2, a0h, a0l);   // chunk 0, m-tile 0 (rolls forward)

  int buf = 0;
  for (int p = 0; p < 8; p++) {          // chunks 2p, 2p+1 (c <= 15, row-type)
    // stage chunks 2p+2, 2p+3 into the other phase buffer
    {
      const uint32_t* src = Bf + (size_t)(2 * p + 2) * BCH_U32 + (size_t)tid * 4;
      uint32_t* dst = &pool[BB_OFF + (buf ^ 1) * PH_U32 + tid * 4];
#pragma unroll
      for (int i = 0; i < 6; i++) gl_lds16(src + i * 1024, dst + i * 1024);
    }
    // chunk c0 = 2p
    buildRow(rp2 + 1 + 2 * p, a1h, a1l);
    doChunk(BB_OFF + buf * PH_U32, a0h, a0l, a1h, a1l);
    a0h = a1h; a0l = a1l;
    // chunk c1 = 2p+1
    buildRow(rp2 + 2 + 2 * p, a1h, a1l);
    doChunk(BB_OFF + buf * PH_U32 + BCH_U32, a0h, a0l, a1h, a1l);
    a0h = a1h; a0l = a1l;

    asm volatile("s_waitcnt vmcnt(0)" ::: "memory");
    __syncthreads();
    buf ^= 1;
  }

  // phase 8: chunks 16 (row-type, rolled) and 17 (strip); stage chunk 18
  {
    const uint32_t* src = Bf + (size_t)18 * BCH_U32 + (size_t)tid * 4;
    uint32_t* dst = &pool[BB_OFF + (buf ^ 1) * PH_U32 + tid * 4];
#pragma unroll
    for (int i = 0; i < 3; i++) gl_lds16(src + i * 1024, dst + i * 1024);

    buildRow(rp2 + 17, a1h, a1l);                   // c=16, m-tile 1
    doChunk(BB_OFF + buf * PH_U32, a0h, a0l, a1h, a1l);

    FragU s0h, s0l, s1h, s1l;
    buildStrip(17, rp2, s0h, s0l);
    buildStrip(17, rp2 + 1, s1h, s1l);
    doChunk(BB_OFF + buf * PH_U32 + BCH_U32, s0h, s0l, s1h, s1l);

    asm volatile("s_waitcnt vmcnt(0)" ::: "memory");
    __syncthreads();
    buf ^= 1;
  }
  // phase 9: chunk 18 (strip), no staging, no barrier
  {
    FragU s0h, s0l, s1h, s1l;
    buildStrip(18, rp2, s0h, s0l);
    buildStrip(18, rp2 + 1, s1h, s1l);
    doChunk(BB_OFF + buf * PH_U32, s0h, s0l, s1h, s1l);
  }

  // ---- fully in-register epilogue (wave owns all 192 filters for its pixels) ----
  const float PI_F = 3.14159265358979323846f;
  float bn[6];
#pragma unroll
  for (int t = 0; t < 6; t++) {
    int n = t * 32 + nl;
    bn[t] = (n < NF) ? bins[n] : 0.f;
  }

#pragma unroll
  for (int mt = 0; mt < 2; mt++) {
#pragma unroll
    for (int q = 0; q < 16; q++) {
      float v[6];
      float S = 0.f, m = -1.f;
      int bt = 0;
#pragma unroll
      for (int t = 0; t < 6; t++) {
        v[t] = fabsf(acc[mt][t][q]);
        S += v[t];
        if (v[t] > m) { m = v[t]; bt = t; }   // first-max within lane (n ascending with t)
      }
      int n = bt * 32 + nl;
      // butterfly over the 32-lane n-group (argmax, smaller-index tie-break; sum)
#pragma unroll
      for (int msk = 1; msk < 32; msk <<= 1) {
        float vo = __shfl_xor(m, msk);
        int   no = __shfl_xor(n, msk);
        float So = __shfl_xor(S, msk);
        bool take = (vo > m) || (vo == m && no < n);
        m = take ? vo : m;
        n = take ? no : n;
        S += So;
      }
      float om  = (float)n / 180.0f * 255.0f;
      float rad = om / 180.0f * PI_F;
      float C = 0.f;
#pragma unroll
      for (int t = 0; t < 6; t++) {
        float dd = rad - bn[t];
        float d0 = fabsf(dd);
        float d1 = fabsf(dd - PI_F);
        float d2 = fabsf(dd + PI_F);
        float d = fminf(d0, fminf(d1, d2));
        C = fmaf(d * d, v[t], C);
      }
#pragma unroll
      for (int msk = 1; msk < 32; msk <<= 1) C += __shfl_xor(C, msk);
      if (nl == 0) {
        int y = y0 + rp2 + mt;
        int x = x0 + ch * 32 + (q & 3) + 8 * (q >> 2) + 4 * half;
        out[(size_t)b * NPIX + (size_t)y * W + x] = om;
        out[(size_t)NB * NPIX + (size_t)b * NPIX + (size_t)y * W + x] = C / S;
      }
    }
  }
}

extern "C" void kernel_launch(void* const* d_in, const int* in_sizes, int n_in,
                              void* d_out, int out_size, void* d_ws, size_t ws_size,
                              hipStream_t stream) {
  const float* x = (const float*)d_in[0];      // [2,3,512,512]
  const float* wts = (const float*)d_in[1];    // [180,1,17,17]
  const float* bins = (const float*)d_in[2];   // [180]
  float* out = (float*)d_out;

  float* ws = (float*)d_ws;
  float* gray = ws;                                 // 524288 f32
  float* tmpA = ws + (size_t)NB * NPIX;             // 524288 f32
  float* tmpB = tmpA + (size_t)NB * NPIX;           // 524288 f32
  uint32_t* dogp = (uint32_t*)(tmpB + (size_t)NB * NPIX);  // 524288 u32
  float* taps = (float*)(dogp + (size_t)NB * NPIX); // 128 f32
  uint32_t* Bf = (uint32_t*)(taps + 128);           // 19*3072 u32

  k_taps<<<1, 64, 0, stream>>>(taps);
  k_repackB<<<114, 256, 0, stream>>>(wts, Bf);

  int n = NB * NPIX;
  int blk = 256, grd = (n + blk - 1) / blk;
  k_gray<<<grd, blk, 0, stream>>>(x, gray);
  k_vblur2<<<grd, blk, 0, stream>>>(gray, tmpA, tmpB, taps);
  k_hblur_dog<<<grd, blk, 0, stream>>>(tmpA, tmpB, dogp, taps);

  k_conv<<<2048, 256, 0, stream>>>(dogp, Bf, bins, out);
}